// Round 10
// baseline (224.496 us; speedup 1.0000x reference)
//
#include <hip/hip_runtime.h>

typedef __attribute__((ext_vector_type(8))) short bf16x8;
typedef __attribute__((ext_vector_type(4))) short bf16x4;
typedef __attribute__((ext_vector_type(4))) float f32x4;
typedef unsigned short ushort_t;
typedef unsigned long long u64_t;

#define B_ 4
#define H_ 8
#define N_ 2048
#define D_ 512
#define MAXREL 199   // MAX_REL-1

__device__ __forceinline__ ushort_t f2bf(float f) {
    union { float f; unsigned u; } v; v.f = f;
    unsigned r = v.u + 0x7fffu + ((v.u >> 16) & 1u);
    return (ushort_t)(r >> 16);
}
__device__ __forceinline__ ushort_t f2bf_fast(float f) {   // round-half-up, positive f
    union { float f; unsigned u; } v; v.f = f;
    return (ushort_t)((v.u + 0x8000u) >> 16);
}
__device__ __forceinline__ float bf2f(ushort_t u) {
    union { unsigned u; float f; } v; v.u = ((unsigned)u) << 16;
    return v.f;
}
// async global->LDS, 16B per lane; lds dest = wave-uniform base + lane*16
__device__ __forceinline__ void gl_lds16(const ushort_t* g, ushort_t* l) {
    __builtin_amdgcn_global_load_lds(
        (const __attribute__((address_space(1))) void*)g,
        (__attribute__((address_space(3))) void*)l,
        16, 0, 0);
}

// ---------------- fused prep: bias_pack | layernorm | wtrans(Wqkv) | wtrans(Wout) ----------------
#define PREP_BIAS  16384                    // (N*N)/256
#define PREP_LN    8192                     // B*N rows
#define PREP_WQ    768                      // (1536/32)*(512/32)
#define PREP_WO    256                      // (512/32)*(512/32)
__global__ __launch_bounds__(256) void prep_kernel(const float* __restrict__ x,
                                                   const float* __restrict__ gamma,
                                                   const float* __restrict__ beta,
                                                   ushort_t* __restrict__ xn,
                                                   const float* __restrict__ Wqkv,
                                                   ushort_t* __restrict__ WqkvT,
                                                   const float* __restrict__ Wout,
                                                   ushort_t* __restrict__ WoutT,
                                                   const float* __restrict__ rel,
                                                   const int* __restrict__ mask,
                                                   ushort_t* __restrict__ bp) {
    __shared__ float smem[32 * 33];
    const int blk = blockIdx.x;
    const int t = threadIdx.x;

    if (blk < PREP_BIAS) {
        // ---- bias+mask pack: plain row-major [n][m] bf16 ----
        int idx = blk * 256 + t;   // n*2048 + m
        int n = idx >> 11, m = idx & 2047;
        int dl = n - m;
        dl = dl < -MAXREL ? -MAXREL : (dl > MAXREL ? MAXREL : dl);
        float v = (mask[idx] == 0) ? -1e9f : rel[dl + MAXREL];
        bp[idx] = f2bf(v);
    } else if (blk < PREP_BIAS + PREP_LN) {
        // ---- LayerNorm row ----
        const int row = blk - PREP_BIAS;
        const float* xr = x + (size_t)row * D_;
        float v0 = xr[t];
        float v1 = xr[t + 256];
        float s = v0 + v1;
        for (int o = 32; o > 0; o >>= 1) s += __shfl_down(s, o);
        if ((t & 63) == 0) smem[t >> 6] = s;
        __syncthreads();
        float mu = (smem[0] + smem[1] + smem[2] + smem[3]) * (1.0f / D_);
        __syncthreads();
        float d0 = v0 - mu, d1 = v1 - mu;
        float s2 = d0 * d0 + d1 * d1;
        for (int o = 32; o > 0; o >>= 1) s2 += __shfl_down(s2, o);
        if ((t & 63) == 0) smem[t >> 6] = s2;
        __syncthreads();
        float var = (smem[0] + smem[1] + smem[2] + smem[3]) * (1.0f / D_);
        float rs = rsqrtf(var + 1e-5f);
        ushort_t* yr = xn + (size_t)row * D_;
        yr[t]       = f2bf(d0 * rs * gamma[t]       + beta[t]);
        yr[t + 256] = f2bf(d1 * rs * gamma[t + 256] + beta[t + 256]);
    } else {
        // ---- weight transpose fp32 [K][Nn] -> bf16 [Nn][K] ----
        const float* W; ushort_t* Wt; int Nn, i;
        if (blk < PREP_BIAS + PREP_LN + PREP_WQ) {
            i = blk - (PREP_BIAS + PREP_LN); W = Wqkv; Wt = WqkvT; Nn = 1536;
        } else {
            i = blk - (PREP_BIAS + PREP_LN + PREP_WQ); W = Wout; Wt = WoutT; Nn = 512;
        }
        const int nb = Nn >> 5;
        const int bx = (i % nb) * 32, by = (i / nb) * 32;
        const int tx = t & 31, ty = t >> 5;
        float (*tile)[33] = (float(*)[33])smem;
        #pragma unroll
        for (int k = 0; k < 32; k += 8)
            tile[ty + k][tx] = W[(size_t)(by + ty + k) * Nn + bx + tx];
        __syncthreads();
        #pragma unroll
        for (int k = 0; k < 32; k += 8)
            Wt[(size_t)(bx + ty + k) * 512 + by + tx] = f2bf(tile[tx][ty + k]);
    }
}

// ---------------- QKV GEMM (MFMA bf16, global_load_lds staging): q scaled by 0.125 ----------------
__global__ __launch_bounds__(256) void gemm_qkv(const ushort_t* __restrict__ A,
                                                const ushort_t* __restrict__ Bt,
                                                ushort_t* __restrict__ qb,
                                                ushort_t* __restrict__ kb,
                                                ushort_t* __restrict__ vb) {
    __shared__ ushort_t As[128 * 32];
    __shared__ ushort_t Bs[128 * 32];
    const int t = threadIdx.x;
    const int lane = t & 63, w = t >> 6;
    const int m16 = lane & 15, quad = lane >> 4;
    const int wr = w >> 1, wc = w & 1;
    const int r0 = blockIdx.y * 128, c0 = blockIdx.x * 128;

    const ushort_t* Ag = A  + (size_t)(r0 + (t >> 2)) * D_ + (t & 3) * 8;
    const ushort_t* Bg = Bt + (size_t)(c0 + (t >> 2)) * D_ + (t & 3) * 8;
    ushort_t* AsW = As + w * 512;
    ushort_t* BsW = Bs + w * 512;

    f32x4 acc[4][4];
    #pragma unroll
    for (int i = 0; i < 4; i++)
        #pragma unroll
        for (int j = 0; j < 4; j++) acc[i][j] = (f32x4){0.f, 0.f, 0.f, 0.f};

    for (int k0 = 0; k0 < D_; k0 += 32) {
        gl_lds16(Ag + k0, AsW);
        gl_lds16(Ag + k0 + (size_t)64 * D_, AsW + 2048);
        gl_lds16(Bg + k0, BsW);
        gl_lds16(Bg + k0 + (size_t)64 * D_, BsW + 2048);
        __syncthreads();
        bf16x8 af[4], bfr[4];
        #pragma unroll
        for (int rt = 0; rt < 4; rt++)
            af[rt] = *(const bf16x8*)(As + (wr * 64 + rt * 16 + m16) * 32 + quad * 8);
        #pragma unroll
        for (int ct = 0; ct < 4; ct++)
            bfr[ct] = *(const bf16x8*)(Bs + (wc * 64 + ct * 16 + m16) * 32 + quad * 8);
        #pragma unroll
        for (int rt = 0; rt < 4; rt++)
            #pragma unroll
            for (int ct = 0; ct < 4; ct++)
                acc[rt][ct] = __builtin_amdgcn_mfma_f32_16x16x32_bf16(af[rt], bfr[ct], acc[rt][ct], 0, 0, 0);
        __syncthreads();
    }

    #pragma unroll
    for (int ct = 0; ct < 4; ct++) {
        int cc = c0 + wc * 64 + ct * 16;      // 16-aligned, uniform per ct
        int which = cc >> 9;
        int h = (cc >> 6) & 7;
        int d = (cc & 63) + m16;
        #pragma unroll
        for (int rt = 0; rt < 4; rt++) {
            int rowb = r0 + wr * 64 + rt * 16 + quad * 4;
            int b = rowb >> 11, n0 = rowb & 2047;
            if (which == 0) {
                #pragma unroll
                for (int r = 0; r < 4; r++)
                    qb[((size_t)((b * H_ + h) * N_ + n0 + r)) * 64 + d] = f2bf(acc[rt][ct][r] * 0.125f);
            } else if (which == 1) {
                #pragma unroll
                for (int r = 0; r < 4; r++)
                    kb[((size_t)((b * H_ + h) * N_ + n0 + r)) * 64 + d] = f2bf(acc[rt][ct][r]);
            } else {
                union { ushort_t u4[4]; unsigned long long ll; } pk;
                #pragma unroll
                for (int r = 0; r < 4; r++) pk.u4[r] = f2bf(acc[rt][ct][r]);
                *(unsigned long long*)(vb + ((size_t)((b * H_ + h) * 64 + d)) * N_ + n0) = pk.ll;
            }
        }
    }
}

// ---------------- Out-proj (MFMA bf16, global_load_lds, BM=64) ----------------
__global__ __launch_bounds__(256) void gemm_out(const ushort_t* __restrict__ A,
                                                const ushort_t* __restrict__ Bt,
                                                const float* __restrict__ bias,
                                                float* __restrict__ C) {
    __shared__ ushort_t As[64 * 32];
    __shared__ ushort_t Bs[128 * 32];
    const int t = threadIdx.x;
    const int lane = t & 63, w = t >> 6;
    const int m16 = lane & 15, quad = lane >> 4;
    const int wr = w >> 1, wc = w & 1;        // wave tile: 32 rows x 64 cols
    const int r0 = blockIdx.y * 64, c0 = blockIdx.x * 128;

    const ushort_t* Ag = A  + (size_t)(r0 + (t >> 2)) * D_ + (t & 3) * 8;
    const ushort_t* Bg = Bt + (size_t)(c0 + (t >> 2)) * D_ + (t & 3) * 8;
    ushort_t* AsW = As + w * 512;
    ushort_t* BsW = Bs + w * 512;

    f32x4 acc[2][4];
    #pragma unroll
    for (int i = 0; i < 2; i++)
        #pragma unroll
        for (int j = 0; j < 4; j++) acc[i][j] = (f32x4){0.f, 0.f, 0.f, 0.f};

    for (int k0 = 0; k0 < D_; k0 += 32) {
        gl_lds16(Ag + k0, AsW);
        gl_lds16(Bg + k0, BsW);
        gl_lds16(Bg + k0 + (size_t)64 * D_, BsW + 2048);
        __syncthreads();
        bf16x8 af[2], bfr[4];
        #pragma unroll
        for (int mf = 0; mf < 2; mf++)
            af[mf] = *(const bf16x8*)(As + (wr * 32 + mf * 16 + m16) * 32 + quad * 8);
        #pragma unroll
        for (int nt = 0; nt < 4; nt++)
            bfr[nt] = *(const bf16x8*)(Bs + (wc * 64 + nt * 16 + m16) * 32 + quad * 8);
        #pragma unroll
        for (int mf = 0; mf < 2; mf++)
            #pragma unroll
            for (int nt = 0; nt < 4; nt++)
                acc[mf][nt] = __builtin_amdgcn_mfma_f32_16x16x32_bf16(af[mf], bfr[nt], acc[mf][nt], 0, 0, 0);
        __syncthreads();
    }

    #pragma unroll
    for (int mf = 0; mf < 2; mf++) {
        #pragma unroll
        for (int nt = 0; nt < 4; nt++) {
            int col = c0 + wc * 64 + nt * 16 + m16;
            int row0 = r0 + wr * 32 + mf * 16 + quad * 4;
            float bv = bias[col];
            #pragma unroll
            for (int r = 0; r < 4; r++)
                C[(size_t)(row0 + r) * 512 + col] = acc[mf][nt][r] + bv;
        }
    }
}

// ---------------- MFMA flash attention v6b: S^T formulation, dual-shuffle P-transpose ----------------
// St = K·Q^T (operand-swapped MFMA): lane (quad,m16) reg (nt,r) holds
// score(key = j0+nt*16+quad*4+r, q = n0w+m16). P -> PV A-frag needs src register
// pk[2g + (quad_dst>>1)] from lanes srcA/srcB; since __shfl transmits the SOURCE's value,
// shuffle BOTH candidate registers and select at the destination (R9 bug: pre-selected
// with own quad -> quads 1,2 got wrong half). Block = 4 waves; 32KB LDS -> 4 blocks/CU.
__global__ __launch_bounds__(256, 4) void attn_mfma(const ushort_t* __restrict__ qb,
                                                    const ushort_t* __restrict__ kb,
                                                    const ushort_t* __restrict__ vb,
                                                    const ushort_t* __restrict__ bp,
                                                    ushort_t* __restrict__ attn) {
    __shared__ ushort_t Ks[2][64 * 64];      // [buf][key][d] swizzled, 8KB each
    __shared__ ushort_t Vs[2][64 * 64];      // [buf][d][key] swizzled, 8KB each

    const int t = threadIdx.x;
    const int w = t >> 6, lane = t & 63;
    const int m16 = lane & 15, quad = lane >> 4;
    const int id = blockIdx.x;
    const int bh = id & 31;                  // XCD affinity: id%8 = bh%8
    const int qt = id >> 5;
    const int b = bh >> 3, h = bh & 7;
    const int n0w = qt * 64 + w * 16;

    // shuffle source lanes for the P-transpose (constants per lane)
    const int srcA = ((2 * quad) & 3) * 16 + m16;
    const int srcB = ((2 * quad + 1) & 3) * 16 + m16;
    const bool selHi = (quad >> 1) != 0;     // dest-side register select

    // staging: thread stages chunks t and t+256; chunk c -> row c>>3, cb c&7
    const int srow0 = t >> 3, scb = t & 7;
    const int srow1 = srow0 + 32;
    const int soff0 = srow0 * 64 + (scb ^ (srow0 & 7)) * 8;
    const int soff1 = srow1 * 64 + (scb ^ (srow1 & 7)) * 8;
    const ushort_t* kgbase = kb + ((size_t)bh * N_) * 64;   // [key][d]
    const ushort_t* vgbase = vb + ((size_t)bh * 64) * N_;   // [d][key]

    // Q frags (one 16-row m-frag per wave), used as MFMA B operand
    const ushort_t* qpb = qb + ((size_t)(bh * N_ + n0w + m16)) * 64 + quad * 8;
    bf16x8 qa0 = *(const bf16x8*)(qpb);
    bf16x8 qa1 = *(const bf16x8*)(qpb + 32);

    // bias row base for this lane's q (= n0w + m16)
    const ushort_t* bprow = bp + (size_t)(n0w + m16) * 2048;

    // prologue: stage tile 0 into buf 0
    *(bf16x8*)(&Ks[0][soff0]) = *(const bf16x8*)(kgbase + (size_t)srow0 * 64 + scb * 8);
    *(bf16x8*)(&Ks[0][soff1]) = *(const bf16x8*)(kgbase + (size_t)srow1 * 64 + scb * 8);
    *(bf16x8*)(&Vs[0][soff0]) = *(const bf16x8*)(vgbase + (size_t)srow0 * N_ + scb * 8);
    *(bf16x8*)(&Vs[0][soff1]) = *(const bf16x8*)(vgbase + (size_t)srow1 * N_ + scb * 8);
    __syncthreads();

    f32x4 o[4];
    #pragma unroll
    for (int nt = 0; nt < 4; nt++) o[nt] = (f32x4){0.f, 0.f, 0.f, 0.f};
    float rsum = 0.f;                        // per-lane: all regs share q = m16

    for (int jt = 0; jt < 32; jt++) {
        const int buf = jt & 1;
        const int j0 = jt * 64;
        const bool more = (jt < 31);

        // ---- issue global staging loads for next tile ----
        bf16x8 kst0, kst1, vst0, vst1;
        if (more) {
            const ushort_t* kg = kgbase + (size_t)(j0 + 64) * 64;
            const ushort_t* vg = vgbase + (j0 + 64);
            kst0 = *(const bf16x8*)(kg + (size_t)srow0 * 64 + scb * 8);
            kst1 = *(const bf16x8*)(kg + (size_t)srow1 * 64 + scb * 8);
            vst0 = *(const bf16x8*)(vg + (size_t)srow0 * N_ + scb * 8);
            vst1 = *(const bf16x8*)(vg + (size_t)srow1 * N_ + scb * 8);
        }

        // ---- bias loads: keys j0 + nt*16 + quad*4 + {0..3} for q = m16 ----
        bf16x4 bcur[4];
        #pragma unroll
        for (int nt = 0; nt < 4; nt++)
            bcur[nt] = *(const bf16x4*)(bprow + j0 + nt * 16 + quad * 4);

        // ---- K frags from LDS + St = K·Q^T ----
        f32x4 s[4];
        #pragma unroll
        for (int nt = 0; nt < 4; nt++) {
            int kr = nt * 16 + m16;
            bf16x8 kf0 = *(const bf16x8*)(&Ks[buf][kr * 64 + ((quad) ^ (kr & 7)) * 8]);
            bf16x8 kf1 = *(const bf16x8*)(&Ks[buf][kr * 64 + ((quad + 4) ^ (kr & 7)) * 8]);
            f32x4 a2 = (f32x4){0.f, 0.f, 0.f, 0.f};
            a2 = __builtin_amdgcn_mfma_f32_16x16x32_bf16(kf0, qa0, a2, 0, 0, 0);
            a2 = __builtin_amdgcn_mfma_f32_16x16x32_bf16(kf1, qa1, a2, 0, 0, 0);
            s[nt] = a2;
        }

        // ---- p = exp(s + bias); per-lane rsum; pack to bf16x4 (64-bit) per nt ----
        u64_t pk[4];
        #pragma unroll
        for (int nt = 0; nt < 4; nt++) {
            union { ushort_t u4[4]; u64_t ll; } pkk;
            #pragma unroll
            for (int r = 0; r < 4; r++) {
                float p = __expf(s[nt][r] + bf2f((ushort_t)bcur[nt][r]));
                rsum += p;
                pkk.u4[r] = f2bf_fast(p);
            }
            pk[nt] = pkk.ll;
        }

        // ---- P A-frags via dual cross-quad shuffles + dest-side select ----
        bf16x8 pa[2];
        #pragma unroll
        for (int g = 0; g < 2; g++) {
            u64_t lo0 = __shfl(pk[2 * g],     srcA);
            u64_t hi0 = __shfl(pk[2 * g + 1], srcA);
            u64_t lo1 = __shfl(pk[2 * g],     srcB);
            u64_t hi1 = __shfl(pk[2 * g + 1], srcB);
            union { u64_t u2[2]; bf16x8 v; } af;
            af.u2[0] = selHi ? hi0 : lo0;
            af.u2[1] = selHi ? hi1 : lo1;
            pa[g] = af.v;
        }

        // ---- V frags from LDS + P·V ----
        #pragma unroll
        for (int nt = 0; nt < 4; nt++) {
            int d = nt * 16 + m16;
            bf16x8 vf0 = *(const bf16x8*)(&Vs[buf][d * 64 + ((quad) ^ (d & 7)) * 8]);
            bf16x8 vf1 = *(const bf16x8*)(&Vs[buf][d * 64 + ((quad + 4) ^ (d & 7)) * 8]);
            o[nt] = __builtin_amdgcn_mfma_f32_16x16x32_bf16(pa[0], vf0, o[nt], 0, 0, 0);
            o[nt] = __builtin_amdgcn_mfma_f32_16x16x32_bf16(pa[1], vf1, o[nt], 0, 0, 0);
        }

        // ---- stage next tile into other buffer; one barrier per tile ----
        if (more) {
            *(bf16x8*)(&Ks[buf ^ 1][soff0]) = kst0;
            *(bf16x8*)(&Ks[buf ^ 1][soff1]) = kst1;
            *(bf16x8*)(&Vs[buf ^ 1][soff0]) = vst0;
            *(bf16x8*)(&Vs[buf ^ 1][soff1]) = vst1;
        }
        __syncthreads();
    }

    // ---- cross-quad row-sum reduce; normalize; store ----
    float r1 = rsum + __shfl_xor(rsum, 16);
    float rsumF = r1 + __shfl_xor(r1, 32);   // all lanes with same m16 hold full sum for q=m16
    #pragma unroll
    for (int r = 0; r < 4; r++) {
        int qloc = quad * 4 + r;             // output row of the PV C-layout
        float inv = 1.0f / __shfl(rsumF, qloc);
        int n = n0w + qloc;
        ushort_t* orow = attn + ((size_t)(b * N_ + n)) * 512 + h * 64 + m16;
        #pragma unroll
        for (int nt = 0; nt < 4; nt++) orow[nt * 16] = f2bf(o[nt][r] * inv);
    }
}

extern "C" void kernel_launch(void* const* d_in, const int* in_sizes, int n_in,
                              void* d_out, int out_size, void* d_ws, size_t ws_size,
                              hipStream_t stream) {
    const float* x     = (const float*)d_in[0];
    const float* gamma = (const float*)d_in[1];
    const float* beta  = (const float*)d_in[2];
    const float* Wqkv  = (const float*)d_in[3];
    const float* Wout  = (const float*)d_in[4];
    const float* bout  = (const float*)d_in[5];
    const float* rel   = (const float*)d_in[6];
    const int*   mask  = (const int*)d_in[7];
    float* out = (float*)d_out;

    char* wsb = (char*)d_ws;
    ushort_t* xn    = (ushort_t*)(wsb);                    //  8 MB
    ushort_t* attnb = (ushort_t*)(wsb + ( 8u << 20));      //  8 MB
    ushort_t* qb    = (ushort_t*)(wsb + (16u << 20));      //  8 MB
    ushort_t* kb    = (ushort_t*)(wsb + (24u << 20));      //  8 MB
    ushort_t* vb    = (ushort_t*)(wsb + (32u << 20));      //  8 MB
    ushort_t* WqkvT = (ushort_t*)(wsb + (40u << 20));      //  1.5 MB
    ushort_t* WoutT = (ushort_t*)(wsb + (42u << 20));      //  0.5 MB
    ushort_t* bp    = (ushort_t*)(wsb + (44u << 20));      //  8 MB

    // 1. fused prep: bias_pack + layernorm + both weight transposes (one launch)
    prep_kernel<<<PREP_BIAS + PREP_LN + PREP_WQ + PREP_WO, 256, 0, stream>>>(
        x, gamma, beta, xn, Wqkv, WqkvT, Wout, WoutT, rel, mask, bp);

    // 2. QKV projection (MFMA + global_load_lds) -> bf16 q(scaled)/k/v (v pre-transposed)
    gemm_qkv<<<dim3(1536 / 128, 8192 / 128), 256, 0, stream>>>(xn, WqkvT, qb, kb, vb);

    // 3. MFMA flash attention v6b -> bf16
    attn_mfma<<<1024, 256, 0, stream>>>(qb, kb, vb, bp, attnb);

    // 4. output projection + bias (MFMA + global_load_lds) -> fp32
    gemm_out<<<dim3(512 / 128, 8192 / 64), 256, 0, stream>>>(attnb, WoutT, bout, out);
}

// Round 11
// 214.367 us; speedup vs baseline: 1.0472x; 1.0472x over previous
//
#include <hip/hip_runtime.h>

typedef __attribute__((ext_vector_type(8))) short bf16x8;
typedef __attribute__((ext_vector_type(4))) short bf16x4;
typedef __attribute__((ext_vector_type(4))) float f32x4;
typedef unsigned short ushort_t;
typedef unsigned long long u64_t;

#define B_ 4
#define H_ 8
#define N_ 2048
#define D_ 512
#define MAXREL 199   // MAX_REL-1
#define LOG2E 1.44269504f

__device__ __forceinline__ ushort_t f2bf(float f) {
    union { float f; unsigned u; } v; v.f = f;
    unsigned r = v.u + 0x7fffu + ((v.u >> 16) & 1u);
    return (ushort_t)(r >> 16);
}
__device__ __forceinline__ ushort_t f2bf_fast(float f) {   // round-half-up, positive f
    union { float f; unsigned u; } v; v.f = f;
    return (ushort_t)((v.u + 0x8000u) >> 16);
}
__device__ __forceinline__ float bf2f(ushort_t u) {
    union { unsigned u; float f; } v; v.u = ((unsigned)u) << 16;
    return v.f;
}
// async global->LDS, 16B per lane; lds dest = wave-uniform base + lane*16
__device__ __forceinline__ void gl_lds16(const ushort_t* g, ushort_t* l) {
    __builtin_amdgcn_global_load_lds(
        (const __attribute__((address_space(1))) void*)g,
        (__attribute__((address_space(3))) void*)l,
        16, 0, 0);
}

// ---------------- fused prep: bias_pack | layernorm | wtrans(Wqkv) | wtrans(Wout) ----------------
#define PREP_BIAS  16384                    // (N*N)/256
#define PREP_LN    8192                     // B*N rows
#define PREP_WQ    768                      // (1536/32)*(512/32)
#define PREP_WO    256                      // (512/32)*(512/32)
__global__ __launch_bounds__(256) void prep_kernel(const float* __restrict__ x,
                                                   const float* __restrict__ gamma,
                                                   const float* __restrict__ beta,
                                                   ushort_t* __restrict__ xn,
                                                   const float* __restrict__ Wqkv,
                                                   ushort_t* __restrict__ WqkvT,
                                                   const float* __restrict__ Wout,
                                                   ushort_t* __restrict__ WoutT,
                                                   const float* __restrict__ rel,
                                                   const int* __restrict__ mask,
                                                   ushort_t* __restrict__ bp) {
    __shared__ float smem[32 * 33];
    const int blk = blockIdx.x;
    const int t = threadIdx.x;

    if (blk < PREP_BIAS) {
        // ---- bias+mask pack: plain row-major [n][m] bf16, pre-scaled by log2(e) ----
        int idx = blk * 256 + t;   // n*2048 + m
        int n = idx >> 11, m = idx & 2047;
        int dl = n - m;
        dl = dl < -MAXREL ? -MAXREL : (dl > MAXREL ? MAXREL : dl);
        float v = (mask[idx] == 0) ? -1e9f : rel[dl + MAXREL];
        bp[idx] = f2bf(v * LOG2E);
    } else if (blk < PREP_BIAS + PREP_LN) {
        // ---- LayerNorm row ----
        const int row = blk - PREP_BIAS;
        const float* xr = x + (size_t)row * D_;
        float v0 = xr[t];
        float v1 = xr[t + 256];
        float s = v0 + v1;
        for (int o = 32; o > 0; o >>= 1) s += __shfl_down(s, o);
        if ((t & 63) == 0) smem[t >> 6] = s;
        __syncthreads();
        float mu = (smem[0] + smem[1] + smem[2] + smem[3]) * (1.0f / D_);
        __syncthreads();
        float d0 = v0 - mu, d1 = v1 - mu;
        float s2 = d0 * d0 + d1 * d1;
        for (int o = 32; o > 0; o >>= 1) s2 += __shfl_down(s2, o);
        if ((t & 63) == 0) smem[t >> 6] = s2;
        __syncthreads();
        float var = (smem[0] + smem[1] + smem[2] + smem[3]) * (1.0f / D_);
        float rs = rsqrtf(var + 1e-5f);
        ushort_t* yr = xn + (size_t)row * D_;
        yr[t]       = f2bf(d0 * rs * gamma[t]       + beta[t]);
        yr[t + 256] = f2bf(d1 * rs * gamma[t + 256] + beta[t + 256]);
    } else {
        // ---- weight transpose fp32 [K][Nn] -> bf16 [Nn][K] ----
        const float* W; ushort_t* Wt; int Nn, i;
        if (blk < PREP_BIAS + PREP_LN + PREP_WQ) {
            i = blk - (PREP_BIAS + PREP_LN); W = Wqkv; Wt = WqkvT; Nn = 1536;
        } else {
            i = blk - (PREP_BIAS + PREP_LN + PREP_WQ); W = Wout; Wt = WoutT; Nn = 512;
        }
        const int nb = Nn >> 5;
        const int bx = (i % nb) * 32, by = (i / nb) * 32;
        const int tx = t & 31, ty = t >> 5;
        float (*tile)[33] = (float(*)[33])smem;
        #pragma unroll
        for (int k = 0; k < 32; k += 8)
            tile[ty + k][tx] = W[(size_t)(by + ty + k) * Nn + bx + tx];
        __syncthreads();
        #pragma unroll
        for (int k = 0; k < 32; k += 8)
            Wt[(size_t)(bx + ty + k) * 512 + by + tx] = f2bf(tile[tx][ty + k]);
    }
}

// ---------------- QKV GEMM (MFMA bf16, global_load_lds staging): q scaled by 0.125*log2e ----------------
__global__ __launch_bounds__(256) void gemm_qkv(const ushort_t* __restrict__ A,
                                                const ushort_t* __restrict__ Bt,
                                                ushort_t* __restrict__ qb,
                                                ushort_t* __restrict__ kb,
                                                ushort_t* __restrict__ vb) {
    __shared__ ushort_t As[128 * 32];
    __shared__ ushort_t Bs[128 * 32];
    const int t = threadIdx.x;
    const int lane = t & 63, w = t >> 6;
    const int m16 = lane & 15, quad = lane >> 4;
    const int wr = w >> 1, wc = w & 1;
    const int r0 = blockIdx.y * 128, c0 = blockIdx.x * 128;

    const ushort_t* Ag = A  + (size_t)(r0 + (t >> 2)) * D_ + (t & 3) * 8;
    const ushort_t* Bg = Bt + (size_t)(c0 + (t >> 2)) * D_ + (t & 3) * 8;
    ushort_t* AsW = As + w * 512;
    ushort_t* BsW = Bs + w * 512;

    f32x4 acc[4][4];
    #pragma unroll
    for (int i = 0; i < 4; i++)
        #pragma unroll
        for (int j = 0; j < 4; j++) acc[i][j] = (f32x4){0.f, 0.f, 0.f, 0.f};

    for (int k0 = 0; k0 < D_; k0 += 32) {
        gl_lds16(Ag + k0, AsW);
        gl_lds16(Ag + k0 + (size_t)64 * D_, AsW + 2048);
        gl_lds16(Bg + k0, BsW);
        gl_lds16(Bg + k0 + (size_t)64 * D_, BsW + 2048);
        __syncthreads();
        bf16x8 af[4], bfr[4];
        #pragma unroll
        for (int rt = 0; rt < 4; rt++)
            af[rt] = *(const bf16x8*)(As + (wr * 64 + rt * 16 + m16) * 32 + quad * 8);
        #pragma unroll
        for (int ct = 0; ct < 4; ct++)
            bfr[ct] = *(const bf16x8*)(Bs + (wc * 64 + ct * 16 + m16) * 32 + quad * 8);
        #pragma unroll
        for (int rt = 0; rt < 4; rt++)
            #pragma unroll
            for (int ct = 0; ct < 4; ct++)
                acc[rt][ct] = __builtin_amdgcn_mfma_f32_16x16x32_bf16(af[rt], bfr[ct], acc[rt][ct], 0, 0, 0);
        __syncthreads();
    }

    #pragma unroll
    for (int ct = 0; ct < 4; ct++) {
        int cc = c0 + wc * 64 + ct * 16;      // 16-aligned, uniform per ct
        int which = cc >> 9;
        int h = (cc >> 6) & 7;
        int d = (cc & 63) + m16;
        #pragma unroll
        for (int rt = 0; rt < 4; rt++) {
            int rowb = r0 + wr * 64 + rt * 16 + quad * 4;
            int b = rowb >> 11, n0 = rowb & 2047;
            if (which == 0) {
                #pragma unroll
                for (int r = 0; r < 4; r++)
                    qb[((size_t)((b * H_ + h) * N_ + n0 + r)) * 64 + d] = f2bf(acc[rt][ct][r] * (0.125f * LOG2E));
            } else if (which == 1) {
                #pragma unroll
                for (int r = 0; r < 4; r++)
                    kb[((size_t)((b * H_ + h) * N_ + n0 + r)) * 64 + d] = f2bf(acc[rt][ct][r]);
            } else {
                union { ushort_t u4[4]; unsigned long long ll; } pk;
                #pragma unroll
                for (int r = 0; r < 4; r++) pk.u4[r] = f2bf(acc[rt][ct][r]);
                *(unsigned long long*)(vb + ((size_t)((b * H_ + h) * 64 + d)) * N_ + n0) = pk.ll;
            }
        }
    }
}

// ---------------- Out-proj (MFMA bf16, global_load_lds, BM=64) ----------------
__global__ __launch_bounds__(256) void gemm_out(const ushort_t* __restrict__ A,
                                                const ushort_t* __restrict__ Bt,
                                                const float* __restrict__ bias,
                                                float* __restrict__ C) {
    __shared__ ushort_t As[64 * 32];
    __shared__ ushort_t Bs[128 * 32];
    const int t = threadIdx.x;
    const int lane = t & 63, w = t >> 6;
    const int m16 = lane & 15, quad = lane >> 4;
    const int wr = w >> 1, wc = w & 1;        // wave tile: 32 rows x 64 cols
    const int r0 = blockIdx.y * 64, c0 = blockIdx.x * 128;

    const ushort_t* Ag = A  + (size_t)(r0 + (t >> 2)) * D_ + (t & 3) * 8;
    const ushort_t* Bg = Bt + (size_t)(c0 + (t >> 2)) * D_ + (t & 3) * 8;
    ushort_t* AsW = As + w * 512;
    ushort_t* BsW = Bs + w * 512;

    f32x4 acc[2][4];
    #pragma unroll
    for (int i = 0; i < 2; i++)
        #pragma unroll
        for (int j = 0; j < 4; j++) acc[i][j] = (f32x4){0.f, 0.f, 0.f, 0.f};

    for (int k0 = 0; k0 < D_; k0 += 32) {
        gl_lds16(Ag + k0, AsW);
        gl_lds16(Bg + k0, BsW);
        gl_lds16(Bg + k0 + (size_t)64 * D_, BsW + 2048);
        __syncthreads();
        bf16x8 af[2], bfr[4];
        #pragma unroll
        for (int mf = 0; mf < 2; mf++)
            af[mf] = *(const bf16x8*)(As + (wr * 32 + mf * 16 + m16) * 32 + quad * 8);
        #pragma unroll
        for (int nt = 0; nt < 4; nt++)
            bfr[nt] = *(const bf16x8*)(Bs + (wc * 64 + nt * 16 + m16) * 32 + quad * 8);
        #pragma unroll
        for (int mf = 0; mf < 2; mf++)
            #pragma unroll
            for (int nt = 0; nt < 4; nt++)
                acc[mf][nt] = __builtin_amdgcn_mfma_f32_16x16x32_bf16(af[mf], bfr[nt], acc[mf][nt], 0, 0, 0);
        __syncthreads();
    }

    #pragma unroll
    for (int mf = 0; mf < 2; mf++) {
        #pragma unroll
        for (int nt = 0; nt < 4; nt++) {
            int col = c0 + wc * 64 + nt * 16 + m16;
            int row0 = r0 + wr * 32 + mf * 16 + quad * 4;
            float bv = bias[col];
            #pragma unroll
            for (int r = 0; r < 4; r++)
                C[(size_t)(row0 + r) * 512 + col] = acc[mf][nt][r] + bv;
        }
    }
}

// ---------------- MFMA flash attention v7: S^T + vectorized LDS P-transpose ----------------
// St = K·Q^T (verified R10): lane (quad,m16) reg (nt,r) = score(key=j0+nt*16+quad*4+r, q=n0w+m16).
// P staged as p_t[q][key] (pad 72): each lane's 4 probs are contiguous -> 4x ds_write_b64/tile;
// PV A-frag = p_t[m16][quad*8..] -> 2x ds_read_b128. (R10's bpermute transpose caused 4.2e6
// LDS conflicts — __shfl IS an LDS op on CDNA.) 512 thr / 8 waves; grid 512; per-lane rsum.
__global__ __launch_bounds__(512, 4) void attn_mfma(const ushort_t* __restrict__ qb,
                                                    const ushort_t* __restrict__ kb,
                                                    const ushort_t* __restrict__ vb,
                                                    const ushort_t* __restrict__ bp,
                                                    ushort_t* __restrict__ attn) {
    __shared__ ushort_t Ks[2][64 * 64];      // [buf][key][d] swizzled, 8KB each
    __shared__ ushort_t Vs[2][64 * 64];      // [buf][d][key] swizzled, 8KB each
    __shared__ ushort_t p_t[8][16 * 72];     // [wave][q][key(+pad)] — per-wave private

    const int t = threadIdx.x;
    const int w = t >> 6, lane = t & 63;
    const int m16 = lane & 15, quad = lane >> 4;
    const int id = blockIdx.x;
    const int bh = id & 31;                  // XCD affinity: id%8 = bh%8
    const int qt = id >> 5;
    const int b = bh >> 3, h = bh & 7;
    const int n0w = qt * 128 + w * 16;

    // staging: each of 512 threads stages one K chunk + one V chunk per tile
    const int srow = t >> 3, scb = t & 7;    // srow 0..63
    const int soff = srow * 64 + (scb ^ (srow & 7)) * 8;
    const ushort_t* kgbase = kb + ((size_t)bh * N_) * 64;   // [key][d]
    const ushort_t* vgbase = vb + ((size_t)bh * 64) * N_;   // [d][key]

    // Q frag (B operand), q = n0w + m16
    const ushort_t* qpb = qb + ((size_t)(bh * N_ + n0w + m16)) * 64 + quad * 8;
    bf16x8 qa0 = *(const bf16x8*)(qpb);
    bf16x8 qa1 = *(const bf16x8*)(qpb + 32);

    // bias row base for this lane's q
    const ushort_t* bprow = bp + (size_t)(n0w + m16) * 2048;

    // prologue: stage tile 0 into buf 0
    *(bf16x8*)(&Ks[0][soff]) = *(const bf16x8*)(kgbase + (size_t)srow * 64 + scb * 8);
    *(bf16x8*)(&Vs[0][soff]) = *(const bf16x8*)(vgbase + (size_t)srow * N_ + scb * 8);
    __syncthreads();

    f32x4 o[4];
    #pragma unroll
    for (int nt = 0; nt < 4; nt++) o[nt] = (f32x4){0.f, 0.f, 0.f, 0.f};
    float rsum = 0.f;                        // per-lane: all regs share q = m16

    ushort_t* pw = p_t[w];

    for (int jt = 0; jt < 32; jt++) {
        const int buf = jt & 1;
        const int j0 = jt * 64;
        const bool more = (jt < 31);

        // ---- issue global staging loads for next tile ----
        bf16x8 kst, vst;
        if (more) {
            kst = *(const bf16x8*)(kgbase + (size_t)(j0 + 64 + srow) * 64 + scb * 8);
            vst = *(const bf16x8*)(vgbase + (size_t)srow * N_ + j0 + 64 + scb * 8);
        }

        // ---- bias loads: keys j0 + nt*16 + quad*4 + {0..3} for q = m16 ----
        bf16x4 bcur[4];
        #pragma unroll
        for (int nt = 0; nt < 4; nt++)
            bcur[nt] = *(const bf16x4*)(bprow + j0 + nt * 16 + quad * 4);

        // ---- K frags from LDS + St = K·Q^T ----
        f32x4 s[4];
        #pragma unroll
        for (int nt = 0; nt < 4; nt++) {
            int kr = nt * 16 + m16;
            bf16x8 kf0 = *(const bf16x8*)(&Ks[buf][kr * 64 + ((quad) ^ (kr & 7)) * 8]);
            bf16x8 kf1 = *(const bf16x8*)(&Ks[buf][kr * 64 + ((quad + 4) ^ (kr & 7)) * 8]);
            f32x4 a2 = (f32x4){0.f, 0.f, 0.f, 0.f};
            a2 = __builtin_amdgcn_mfma_f32_16x16x32_bf16(kf0, qa0, a2, 0, 0, 0);
            a2 = __builtin_amdgcn_mfma_f32_16x16x32_bf16(kf1, qa1, a2, 0, 0, 0);
            s[nt] = a2;
        }

        // ---- p = exp2(s + bias); per-lane rsum; one b64 LDS write per nt ----
        #pragma unroll
        for (int nt = 0; nt < 4; nt++) {
            union { ushort_t u4[4]; u64_t ll; } pkk;
            #pragma unroll
            for (int r = 0; r < 4; r++) {
                float p = exp2f(s[nt][r] + bf2f((ushort_t)bcur[nt][r]));
                rsum += p;
                pkk.u4[r] = f2bf_fast(p);
            }
            *(u64_t*)(&pw[m16 * 72 + nt * 16 + quad * 4]) = pkk.ll;
        }

        // ---- P A-frags: direct b128 reads (per-wave private, same-wave ordering) ----
        bf16x8 pa0 = *(const bf16x8*)(&pw[m16 * 72 + quad * 8]);
        bf16x8 pa1 = *(const bf16x8*)(&pw[m16 * 72 + 32 + quad * 8]);

        // ---- V frags from LDS + P·V ----
        #pragma unroll
        for (int nt = 0; nt < 4; nt++) {
            int d = nt * 16 + m16;
            bf16x8 vf0 = *(const bf16x8*)(&Vs[buf][d * 64 + ((quad) ^ (d & 7)) * 8]);
            bf16x8 vf1 = *(const bf16x8*)(&Vs[buf][d * 64 + ((quad + 4) ^ (d & 7)) * 8]);
            o[nt] = __builtin_amdgcn_mfma_f32_16x16x32_bf16(pa0, vf0, o[nt], 0, 0, 0);
            o[nt] = __builtin_amdgcn_mfma_f32_16x16x32_bf16(pa1, vf1, o[nt], 0, 0, 0);
        }

        // ---- stage next tile into other buffer; one barrier per tile ----
        if (more) {
            *(bf16x8*)(&Ks[buf ^ 1][soff]) = kst;
            *(bf16x8*)(&Vs[buf ^ 1][soff]) = vst;
        }
        __syncthreads();
    }

    // ---- cross-quad row-sum reduce; normalize; store (indexing verified R10) ----
    float r1 = rsum + __shfl_xor(rsum, 16);
    float rsumF = r1 + __shfl_xor(r1, 32);   // all lanes with same m16 hold full sum for q=m16
    #pragma unroll
    for (int r = 0; r < 4; r++) {
        int qloc = quad * 4 + r;             // output row of the PV C-layout
        float inv = 1.0f / __shfl(rsumF, qloc);
        int n = n0w + qloc;
        ushort_t* orow = attn + ((size_t)(b * N_ + n)) * 512 + h * 64 + m16;
        #pragma unroll
        for (int nt = 0; nt < 4; nt++) orow[nt * 16] = f2bf(o[nt][r] * inv);
    }
}

extern "C" void kernel_launch(void* const* d_in, const int* in_sizes, int n_in,
                              void* d_out, int out_size, void* d_ws, size_t ws_size,
                              hipStream_t stream) {
    const float* x     = (const float*)d_in[0];
    const float* gamma = (const float*)d_in[1];
    const float* beta  = (const float*)d_in[2];
    const float* Wqkv  = (const float*)d_in[3];
    const float* Wout  = (const float*)d_in[4];
    const float* bout  = (const float*)d_in[5];
    const float* rel   = (const float*)d_in[6];
    const int*   mask  = (const int*)d_in[7];
    float* out = (float*)d_out;

    char* wsb = (char*)d_ws;
    ushort_t* xn    = (ushort_t*)(wsb);                    //  8 MB
    ushort_t* attnb = (ushort_t*)(wsb + ( 8u << 20));      //  8 MB
    ushort_t* qb    = (ushort_t*)(wsb + (16u << 20));      //  8 MB
    ushort_t* kb    = (ushort_t*)(wsb + (24u << 20));      //  8 MB
    ushort_t* vb    = (ushort_t*)(wsb + (32u << 20));      //  8 MB
    ushort_t* WqkvT = (ushort_t*)(wsb + (40u << 20));      //  1.5 MB
    ushort_t* WoutT = (ushort_t*)(wsb + (42u << 20));      //  0.5 MB
    ushort_t* bp    = (ushort_t*)(wsb + (44u << 20));      //  8 MB

    // 1. fused prep: bias_pack + layernorm + both weight transposes (one launch)
    prep_kernel<<<PREP_BIAS + PREP_LN + PREP_WQ + PREP_WO, 256, 0, stream>>>(
        x, gamma, beta, xn, Wqkv, WqkvT, Wout, WoutT, rel, mask, bp);

    // 2. QKV projection (MFMA + global_load_lds) -> bf16 q(scaled)/k/v (v pre-transposed)
    gemm_qkv<<<dim3(1536 / 128, 8192 / 128), 256, 0, stream>>>(xn, WqkvT, qb, kb, vb);

    // 3. MFMA flash attention v7 -> bf16
    attn_mfma<<<512, 512, 0, stream>>>(qb, kb, vb, bp, attnb);

    // 4. output projection + bias (MFMA + global_load_lds) -> fp32
    gemm_out<<<dim3(512 / 128, 8192 / 64), 256, 0, stream>>>(attnb, WoutT, bout, out);
}